// Round 1
// baseline (2050.608 us; speedup 1.0000x reference)
//
#include <hip/hip_runtime.h>
#include <hip/hip_bf16.h>

// GENConv fused: out = softmax(adj) @ x @ W + b
//   = diag(1/rowsum(exp(adj))) * (exp(adj) @ (x@W)) + b     (adj in [0,1) -> no max needed)
// Kernel 1: yT[k][j] = bf16( (x @ W)[j][k] )   (transposed, bf16, in d_ws)
// Kernel 2: fused exp + MFMA GEMM + rowsum + scale + bias.
//   K-SPLIT VERSION: each block owns 16 rows; wave w handles k in [4096w, 4096(w+1)).
//   grid 1024 -> 4 blocks/CU = 16 waves/CU (was 4 waves/CU, latency-bound at 12% occ).
//   Cross-wave reduction of acc + rowsum via LDS tree in the epilogue.

typedef short  short8  __attribute__((ext_vector_type(8)));
typedef float  floatx4 __attribute__((ext_vector_type(4)));

#define NN 16384
#define DD 128
#define KCH (NN / 4)      // k-chunk per wave
#define KST (KCH / 32)    // 128 MFMA k-steps per wave

__device__ __forceinline__ short f2bf(float f) {
    unsigned u = __float_as_uint(f);
    u += 0x7fff + ((u >> 16) & 1);      // RNE
    return (short)(u >> 16);
}

// ---------------- Kernel 1: yT = (x @ W)^T in bf16 ----------------
// grid 256, block 256. Block handles 64 j-rows. MFMA: A = W^T (staged LDS), B = x rows.
__global__ __launch_bounds__(256, 2) void xw_kernel(
    const float* __restrict__ x, const float* __restrict__ W, short* __restrict__ yT)
{
    __shared__ short WT[128 * 136];           // WT[k][d], padded row = 136 shorts
    const int t  = threadIdx.x;
    const int j0 = blockIdx.x * 64;

    // stage W^T as bf16 (transpose during store; one-time)
    #pragma unroll
    for (int i = 0; i < 16; ++i) {
        int f4 = t + 256 * i;                 // 0..4095 float4s of W (128x128)
        int d = f4 >> 5, c4 = f4 & 31;
        float4 v = ((const float4*)W)[f4];
        WT[(4*c4 + 0) * 136 + d] = f2bf(v.x);
        WT[(4*c4 + 1) * 136 + d] = f2bf(v.y);
        WT[(4*c4 + 2) * 136 + d] = f2bf(v.z);
        WT[(4*c4 + 3) * 136 + d] = f2bf(v.w);
    }
    __syncthreads();

    const int lane = t & 63, w = t >> 6;
    const int nl = lane & 15, q = lane >> 4;
    const int j = j0 + 16 * w + nl;           // this lane's x row (B-operand n index)
    const float* xrow = x + (size_t)j * DD + 8 * q;

    floatx4 acc[8];
    #pragma unroll
    for (int kt = 0; kt < 8; ++kt) acc[kt] = (floatx4){0.f, 0.f, 0.f, 0.f};

    #pragma unroll
    for (int dstep = 0; dstep < 4; ++dstep) {
        float4 v0 = *(const float4*)(xrow + 32 * dstep);
        float4 v1 = *(const float4*)(xrow + 32 * dstep + 4);
        short8 bf;
        bf[0] = f2bf(v0.x); bf[1] = f2bf(v0.y); bf[2] = f2bf(v0.z); bf[3] = f2bf(v0.w);
        bf[4] = f2bf(v1.x); bf[5] = f2bf(v1.y); bf[6] = f2bf(v1.z); bf[7] = f2bf(v1.w);
        #pragma unroll
        for (int kt = 0; kt < 8; ++kt) {
            short8 af = *(const short8*)(&WT[(16*kt + nl) * 136 + 32*dstep + 8*q]);
            acc[kt] = __builtin_amdgcn_mfma_f32_16x16x32_bf16(af, bf, acc[kt], 0, 0, 0);
        }
    }
    // D layout: row(m=k) = 4q + r (+16kt), col(n=j) = nl -> store transposed: yT[k][j]
    #pragma unroll
    for (int kt = 0; kt < 8; ++kt) {
        #pragma unroll
        for (int r = 0; r < 4; ++r)
            yT[(size_t)(16*kt + 4*q + r) * NN + j] = f2bf(acc[kt][r]);
    }
}

// ---------------- Kernel 2: k-split fused exp-GEMM ----------------
// grid 1024 blocks x 256 threads; block owns rows [bid*16, +16), all 128 cols.
// Wave w streams k in [w*4096, (w+1)*4096) in 128 steps of 32; LDS tree-reduce at end.
__global__ __launch_bounds__(256, 4) void attn_kernel(
    const float* __restrict__ adj, const short* __restrict__ yT,
    const float* __restrict__ bias, float* __restrict__ out)
{
    __shared__ float redA[32 * 64];           // 8 KB: one wave's acc payload
    __shared__ float redB[32 * 64];           // 8 KB
    __shared__ float rsum[4][16];             // per-wave partial rowsums

    const int t  = threadIdx.x;
    const int la = t & 63, w = t >> 6;
    const int m = la & 15, q = la >> 4;
    const int i0 = blockIdx.x * 16;           // block's 16 output rows

    // A: lane reads adj[i0+m][w*4096 + 32s + 8q .. +7]  (two float4, HBM)
    const float* aptr = adj + (size_t)(i0 + m) * NN + w * KCH + 8 * q;
    // B: lane reads yT[16nt+m][w*4096 + 32s + 8q .. +7]  (one uint4 = 8 bf16, L2)
    const short* bptr = yT + (size_t)m * NN + w * KCH + 8 * q;

    floatx4 acc[8];
    #pragma unroll
    for (int nt = 0; nt < 8; ++nt) acc[nt] = (floatx4){0.f, 0.f, 0.f, 0.f};
    float psumA = 0.f, psumB = 0.f;

    // 2-slot register pipeline
    float4 A00, A01, A10, A11;
    uint4  B0[8], B1[8];

    auto load_slot = [&](int s, float4& Aa, float4& Ab, uint4* B) {
        const float* ap = aptr + (size_t)s * 32;
        Aa = *(const float4*)ap;
        Ab = *(const float4*)(ap + 4);
        const short* bp = bptr + (size_t)s * 32;
        #pragma unroll
        for (int nt = 0; nt < 8; ++nt)
            B[nt] = *(const uint4*)(bp + (size_t)nt * (16 * NN));
    };
    auto step = [&](const float4& Aa, const float4& Ab, const uint4* B, float& psum) {
        float e0 = __expf(Aa.x), e1 = __expf(Aa.y), e2 = __expf(Aa.z), e3 = __expf(Aa.w);
        float e4 = __expf(Ab.x), e5 = __expf(Ab.y), e6 = __expf(Ab.z), e7 = __expf(Ab.w);
        psum += ((e0 + e1) + (e2 + e3)) + ((e4 + e5) + (e6 + e7));
        short8 af;
        af[0] = f2bf(e0); af[1] = f2bf(e1); af[2] = f2bf(e2); af[3] = f2bf(e3);
        af[4] = f2bf(e4); af[5] = f2bf(e5); af[6] = f2bf(e6); af[7] = f2bf(e7);
        #pragma unroll
        for (int nt = 0; nt < 8; ++nt) {
            short8 bf = *(const short8*)&B[nt];
            acc[nt] = __builtin_amdgcn_mfma_f32_16x16x32_bf16(af, bf, acc[nt], 0, 0, 0);
        }
    };

    load_slot(0, A00, A01, B0);
    load_slot(1, A10, A11, B1);
    #pragma unroll 1
    for (int s = 0; s < KST; s += 2) {
        step(A00, A01, B0, psumA);
        if (s + 2 < KST) load_slot(s + 2, A00, A01, B0);
        step(A10, A11, B1, psumB);
        if (s + 3 < KST) load_slot(s + 3, A10, A11, B1);
    }

    // per-wave partial rowsum: lane(m,q) covered k = 8q..8q+7 (mod 32) of chunk w;
    // reduce across q lanes -> every lane holds partial rowsum of row m for chunk w
    float sum = psumA + psumB;
    sum += __shfl_xor(sum, 16);
    sum += __shfl_xor(sum, 32);
    if (la < 16) rsum[w][la] = sum;           // la<16 => q==0, m==la

    // ---- cross-wave accumulator reduction (LDS tree), lane-linear = conflict-free ----
    if (w == 2) {
        #pragma unroll
        for (int nt = 0; nt < 8; ++nt)
            #pragma unroll
            for (int r = 0; r < 4; ++r) redA[(nt * 4 + r) * 64 + la] = acc[nt][r];
    }
    if (w == 3) {
        #pragma unroll
        for (int nt = 0; nt < 8; ++nt)
            #pragma unroll
            for (int r = 0; r < 4; ++r) redB[(nt * 4 + r) * 64 + la] = acc[nt][r];
    }
    __syncthreads();
    if (w == 0) {
        #pragma unroll
        for (int nt = 0; nt < 8; ++nt)
            #pragma unroll
            for (int r = 0; r < 4; ++r) acc[nt][r] += redA[(nt * 4 + r) * 64 + la];
    }
    if (w == 1) {
        #pragma unroll
        for (int nt = 0; nt < 8; ++nt)
            #pragma unroll
            for (int r = 0; r < 4; ++r) acc[nt][r] += redB[(nt * 4 + r) * 64 + la];
    }
    __syncthreads();
    if (w == 1) {
        #pragma unroll
        for (int nt = 0; nt < 8; ++nt)
            #pragma unroll
            for (int r = 0; r < 4; ++r) redA[(nt * 4 + r) * 64 + la] = acc[nt][r];
    }
    __syncthreads();
    if (w == 0) {
        #pragma unroll
        for (int nt = 0; nt < 8; ++nt)
            #pragma unroll
            for (int r = 0; r < 4; ++r) acc[nt][r] += redA[(nt * 4 + r) * 64 + la];

        // total rowsum + inverse for this lane's 4 output rows (rows 4q+r)
        float invr[4];
        #pragma unroll
        for (int r = 0; r < 4; ++r) {
            int row = 4 * q + r;
            invr[r] = 1.0f / (rsum[0][row] + rsum[1][row] + rsum[2][row] + rsum[3][row]);
        }

        // D layout: col(n) = m, row = 4q + r
        #pragma unroll
        for (int nt = 0; nt < 8; ++nt) {
            float bv = bias[16 * nt + m];
            #pragma unroll
            for (int r = 0; r < 4; ++r)
                out[(size_t)(i0 + 4 * q + r) * DD + 16 * nt + m] = acc[nt][r] * invr[r] + bv;
        }
    }
}

extern "C" void kernel_launch(void* const* d_in, const int* in_sizes, int n_in,
                              void* d_out, int out_size, void* d_ws, size_t ws_size,
                              hipStream_t stream)
{
    const float* x    = (const float*)d_in[0];
    const float* adj  = (const float*)d_in[1];
    const float* W    = (const float*)d_in[2];
    const float* bias = (const float*)d_in[3];
    float* out = (float*)d_out;
    short* yT  = (short*)d_ws;                 // 128 x 16384 bf16 = 4 MiB

    hipLaunchKernelGGL(xw_kernel,   dim3(256),  dim3(256), 0, stream, x, W, yT);
    hipLaunchKernelGGL(attn_kernel, dim3(1024), dim3(256), 0, stream, adj, yT, bias, out);
}

// Round 2
// 1750.464 us; speedup vs baseline: 1.1715x; 1.1715x over previous
//
#include <hip/hip_runtime.h>
#include <hip/hip_bf16.h>

// GENConv fused: out = softmax(adj) @ x @ W + b
//   = diag(1/rowsum(exp(adj))) * (exp(adj) @ (x@W)) + b     (adj in [0,1) -> no max needed)
// Kernel 1: yT[k][j] = bf16( (x @ W)[j][k] )   (transposed, bf16, in d_ws)
// Kernel 2: fused exp + MFMA GEMM + rowsum + scale + bias.
//   K-SPLIT: block owns 16 rows; wave w handles k in [4096w, 4096(w+1)).
//   grid 1024 -> 4 blocks/CU = 16 waves/CU.
//   ROUND 2 FIX: round 1 spilled (VGPR demand ~145 > 128 cap at 4 waves/SIMD ->
//   852 MB scratch writes). Now SINGLE-buffer B (32 VGPR), double-buffer A only
//   (16 VGPR). exp/pack VALU on resident A covers B load latency; 4-wave TLP
//   covers the rest. Demand ~110 regs -> no spill.

typedef short  short8  __attribute__((ext_vector_type(8)));
typedef float  floatx4 __attribute__((ext_vector_type(4)));

#define NN 16384
#define DD 128
#define KCH (NN / 4)      // k-chunk per wave
#define KST (KCH / 32)    // 128 MFMA k-steps per wave

__device__ __forceinline__ short f2bf(float f) {
    unsigned u = __float_as_uint(f);
    u += 0x7fff + ((u >> 16) & 1);      // RNE
    return (short)(u >> 16);
}

// ---------------- Kernel 1: yT = (x @ W)^T in bf16 ----------------
// grid 256, block 256. Block handles 64 j-rows. MFMA: A = W^T (staged LDS), B = x rows.
__global__ __launch_bounds__(256, 2) void xw_kernel(
    const float* __restrict__ x, const float* __restrict__ W, short* __restrict__ yT)
{
    __shared__ short WT[128 * 136];           // WT[k][d], padded row = 136 shorts
    const int t  = threadIdx.x;
    const int j0 = blockIdx.x * 64;

    // stage W^T as bf16 (transpose during store; one-time)
    #pragma unroll
    for (int i = 0; i < 16; ++i) {
        int f4 = t + 256 * i;                 // 0..4095 float4s of W (128x128)
        int d = f4 >> 5, c4 = f4 & 31;
        float4 v = ((const float4*)W)[f4];
        WT[(4*c4 + 0) * 136 + d] = f2bf(v.x);
        WT[(4*c4 + 1) * 136 + d] = f2bf(v.y);
        WT[(4*c4 + 2) * 136 + d] = f2bf(v.z);
        WT[(4*c4 + 3) * 136 + d] = f2bf(v.w);
    }
    __syncthreads();

    const int lane = t & 63, w = t >> 6;
    const int nl = lane & 15, q = lane >> 4;
    const int j = j0 + 16 * w + nl;           // this lane's x row (B-operand n index)
    const float* xrow = x + (size_t)j * DD + 8 * q;

    floatx4 acc[8];
    #pragma unroll
    for (int kt = 0; kt < 8; ++kt) acc[kt] = (floatx4){0.f, 0.f, 0.f, 0.f};

    #pragma unroll
    for (int dstep = 0; dstep < 4; ++dstep) {
        float4 v0 = *(const float4*)(xrow + 32 * dstep);
        float4 v1 = *(const float4*)(xrow + 32 * dstep + 4);
        short8 bf;
        bf[0] = f2bf(v0.x); bf[1] = f2bf(v0.y); bf[2] = f2bf(v0.z); bf[3] = f2bf(v0.w);
        bf[4] = f2bf(v1.x); bf[5] = f2bf(v1.y); bf[6] = f2bf(v1.z); bf[7] = f2bf(v1.w);
        #pragma unroll
        for (int kt = 0; kt < 8; ++kt) {
            short8 af = *(const short8*)(&WT[(16*kt + nl) * 136 + 32*dstep + 8*q]);
            acc[kt] = __builtin_amdgcn_mfma_f32_16x16x32_bf16(af, bf, acc[kt], 0, 0, 0);
        }
    }
    // D layout: row(m=k) = 4q + r (+16kt), col(n=j) = nl -> store transposed: yT[k][j]
    #pragma unroll
    for (int kt = 0; kt < 8; ++kt) {
        #pragma unroll
        for (int r = 0; r < 4; ++r)
            yT[(size_t)(16*kt + 4*q + r) * NN + j] = f2bf(acc[kt][r]);
    }
}

// ---------------- Kernel 2: k-split fused exp-GEMM ----------------
// grid 1024 blocks x 256 threads; block owns rows [bid*16, +16), all 128 cols.
// Wave w streams k in [w*4096, (w+1)*4096) in 128 steps of 32; LDS tree-reduce at end.
__global__ __launch_bounds__(256, 4) void attn_kernel(
    const float* __restrict__ adj, const short* __restrict__ yT,
    const float* __restrict__ bias, float* __restrict__ out)
{
    __shared__ float redA[32 * 64];           // 8 KB: one wave's acc payload
    __shared__ float redB[32 * 64];           // 8 KB
    __shared__ float rsum[4][16];             // per-wave partial rowsums

    const int t  = threadIdx.x;
    const int la = t & 63, w = t >> 6;
    const int m = la & 15, q = la >> 4;
    const int i0 = blockIdx.x * 16;           // block's 16 output rows

    // A: lane reads adj[i0+m][w*4096 + 32s + 8q .. +7]  (two float4, HBM)
    const float* aptr = adj + (size_t)(i0 + m) * NN + w * KCH + 8 * q;
    // B: lane reads yT[16nt+m][w*4096 + 32s + 8q .. +7]  (one uint4 = 8 bf16, L2)
    const short* bptr = yT + (size_t)m * NN + w * KCH + 8 * q;

    floatx4 acc[8];
    #pragma unroll
    for (int nt = 0; nt < 8; ++nt) acc[nt] = (floatx4){0.f, 0.f, 0.f, 0.f};
    float psumA = 0.f, psumB = 0.f;

    // registers: A double-buffered (2 x float4x2 = 16), B single-buffered (8 x uint4 = 32)
    float4 A00, A01, A10, A11;
    uint4  B[8];

    // exp + pack + partial sum on a resident A fragment
    auto exppack = [&](const float4& Aa, const float4& Ab, short8& af) -> float {
        float e0 = __expf(Aa.x), e1 = __expf(Aa.y), e2 = __expf(Aa.z), e3 = __expf(Aa.w);
        float e4 = __expf(Ab.x), e5 = __expf(Ab.y), e6 = __expf(Ab.z), e7 = __expf(Ab.w);
        af[0] = f2bf(e0); af[1] = f2bf(e1); af[2] = f2bf(e2); af[3] = f2bf(e3);
        af[4] = f2bf(e4); af[5] = f2bf(e5); af[6] = f2bf(e6); af[7] = f2bf(e7);
        return ((e0 + e1) + (e2 + e3)) + ((e4 + e5) + (e6 + e7));
    };

    // prefetch A for steps 0 and 1
    A00 = *(const float4*)(aptr);
    A01 = *(const float4*)(aptr + 4);
    A10 = *(const float4*)(aptr + 32);
    A11 = *(const float4*)(aptr + 36);

    #pragma unroll 1
    for (int s = 0; s < KST; s += 2) {
        // ---- step s ----
        {
            const short* bp = bptr + (size_t)s * 32;
            #pragma unroll
            for (int nt = 0; nt < 8; ++nt)
                B[nt] = *(const uint4*)(bp + (size_t)nt * (16 * NN));   // issue B loads
        }
        short8 af0;
        float ps0 = exppack(A00, A01, af0);                             // VALU under B latency
        if (s + 2 < KST) {                                              // prefetch A(s+2)
            const float* ap = aptr + (size_t)(s + 2) * 32;
            A00 = *(const float4*)ap;
            A01 = *(const float4*)(ap + 4);
        }
        psumA += ps0;
        #pragma unroll
        for (int nt = 0; nt < 8; ++nt) {
            short8 bf = *(const short8*)&B[nt];
            acc[nt] = __builtin_amdgcn_mfma_f32_16x16x32_bf16(af0, bf, acc[nt], 0, 0, 0);
        }
        // ---- step s+1 ----
        {
            const short* bp = bptr + (size_t)(s + 1) * 32;
            #pragma unroll
            for (int nt = 0; nt < 8; ++nt)
                B[nt] = *(const uint4*)(bp + (size_t)nt * (16 * NN));
        }
        short8 af1;
        float ps1 = exppack(A10, A11, af1);
        if (s + 3 < KST) {                                              // prefetch A(s+3)
            const float* ap = aptr + (size_t)(s + 3) * 32;
            A10 = *(const float4*)ap;
            A11 = *(const float4*)(ap + 4);
        }
        psumB += ps1;
        #pragma unroll
        for (int nt = 0; nt < 8; ++nt) {
            short8 bf = *(const short8*)&B[nt];
            acc[nt] = __builtin_amdgcn_mfma_f32_16x16x32_bf16(af1, bf, acc[nt], 0, 0, 0);
        }
    }

    // per-wave partial rowsum: lane(m,q) covered k = 8q..8q+7 (mod 32) of chunk w;
    // reduce across q lanes -> every lane holds partial rowsum of row m for chunk w
    float sum = psumA + psumB;
    sum += __shfl_xor(sum, 16);
    sum += __shfl_xor(sum, 32);
    if (la < 16) rsum[w][la] = sum;           // la<16 => q==0, m==la

    // ---- cross-wave accumulator reduction (LDS tree), lane-linear = conflict-free ----
    if (w == 2) {
        #pragma unroll
        for (int nt = 0; nt < 8; ++nt)
            #pragma unroll
            for (int r = 0; r < 4; ++r) redA[(nt * 4 + r) * 64 + la] = acc[nt][r];
    }
    if (w == 3) {
        #pragma unroll
        for (int nt = 0; nt < 8; ++nt)
            #pragma unroll
            for (int r = 0; r < 4; ++r) redB[(nt * 4 + r) * 64 + la] = acc[nt][r];
    }
    __syncthreads();
    if (w == 0) {
        #pragma unroll
        for (int nt = 0; nt < 8; ++nt)
            #pragma unroll
            for (int r = 0; r < 4; ++r) acc[nt][r] += redA[(nt * 4 + r) * 64 + la];
    }
    if (w == 1) {
        #pragma unroll
        for (int nt = 0; nt < 8; ++nt)
            #pragma unroll
            for (int r = 0; r < 4; ++r) acc[nt][r] += redB[(nt * 4 + r) * 64 + la];
    }
    __syncthreads();
    if (w == 1) {
        #pragma unroll
        for (int nt = 0; nt < 8; ++nt)
            #pragma unroll
            for (int r = 0; r < 4; ++r) redA[(nt * 4 + r) * 64 + la] = acc[nt][r];
    }
    __syncthreads();
    if (w == 0) {
        #pragma unroll
        for (int nt = 0; nt < 8; ++nt)
            #pragma unroll
            for (int r = 0; r < 4; ++r) acc[nt][r] += redA[(nt * 4 + r) * 64 + la];

        // total rowsum + inverse for this lane's 4 output rows (rows 4q+r)
        float invr[4];
        #pragma unroll
        for (int r = 0; r < 4; ++r) {
            int row = 4 * q + r;
            invr[r] = 1.0f / (rsum[0][row] + rsum[1][row] + rsum[2][row] + rsum[3][row]);
        }

        // D layout: col(n) = m, row = 4q + r
        #pragma unroll
        for (int nt = 0; nt < 8; ++nt) {
            float bv = bias[16 * nt + m];
            #pragma unroll
            for (int r = 0; r < 4; ++r)
                out[(size_t)(i0 + 4 * q + r) * DD + 16 * nt + m] = acc[nt][r] * invr[r] + bv;
        }
    }
}

extern "C" void kernel_launch(void* const* d_in, const int* in_sizes, int n_in,
                              void* d_out, int out_size, void* d_ws, size_t ws_size,
                              hipStream_t stream)
{
    const float* x    = (const float*)d_in[0];
    const float* adj  = (const float*)d_in[1];
    const float* W    = (const float*)d_in[2];
    const float* bias = (const float*)d_in[3];
    float* out = (float*)d_out;
    short* yT  = (short*)d_ws;                 // 128 x 16384 bf16 = 4 MiB

    hipLaunchKernelGGL(xw_kernel,   dim3(256),  dim3(256), 0, stream, x, W, yT);
    hipLaunchKernelGGL(attn_kernel, dim3(1024), dim3(256), 0, stream, adj, yT, bias, out);
}